// Round 2
// baseline (59.456 us; speedup 1.0000x reference)
//
#include <hip/hip_runtime.h>
#include <hip/hip_bf16.h>

// Analytic reduction of the reference:
//   angles = pi*tanh(MLP(x));  <Z0> = sin(theta1)*sin(theta2)  (theta0, q_params cancel)
//   out = sigmoid(5*<Z0>)
// Memory-bound on reading x (205 MB). Round 2: BM=64 (4 blocks/CU), raw-barrier
// discipline (lgkmcnt-only drains) so 2-deep register prefetch stays in flight
// across barriers (counted vmcnt via register deps).

#define BM 64
#define KDIM 784
#define BK 32
#define NITER 25      // ceil(784/32); 784 = 24*32 + 16, tail zero-padded
#define ASTR 80       // LDS tile row stride bytes (32 bf16 + 16B pad -> 2-way banks, free)

using f32x4 = __attribute__((ext_vector_type(4))) float;
using s16x8 = __attribute__((ext_vector_type(8))) short;

struct Lds {
    union {
        struct { char a[BM * ASTR]; char b[64 * ASTR]; } st;  // 5120 + 5120 B
        float h1[BM * 65];                                    // 16640 B, stride 65
    } u;
    float part[4][BM][2];                                     // layer-3 partials, 2 KB
};

__device__ __forceinline__ ushort f2bf(float f) {
    uint b = __float_as_uint(f);
    b += 0x7FFFu + ((b >> 16) & 1u);   // RNE
    return (ushort)(b >> 16);
}
__device__ __forceinline__ uint pack2(float lo, float hi) {
    return (uint)f2bf(lo) | ((uint)f2bf(hi) << 16);
}

__global__ void __launch_bounds__(256, 4) hybrid_kernel(
    const float* __restrict__ x, const float* __restrict__ W1,
    const float* __restrict__ b1, const float* __restrict__ W2,
    const float* __restrict__ b2, const float* __restrict__ W3,
    const float* __restrict__ b3, float* __restrict__ out, int B)
{
    __shared__ Lds lds;
    const int tid  = threadIdx.x;
    const int wave = tid >> 6, lane = tid & 63;
    const int row0 = blockIdx.x * BM;

    // staging: 4 threads per row, 8 consecutive f32 (2 float4) each
    const int srow = tid >> 2, sslot = tid & 3;

    f32x4 acc[4];
    #pragma unroll
    for (int n = 0; n < 4; ++n)
        #pragma unroll
        for (int j = 0; j < 4; ++j) acc[n][j] = 0.f;

    float4 Ra[4], Rb[4];   // parity-static 2-deep prefetch sets (A0,A1,B0,B1)

    const int garow = row0 + srow;
    const float* xrow = x + (size_t)garow * KDIM;
    const float* wrow = W1 + (size_t)srow * KDIM;

    auto loadTile = [&](int it, float4 (&R)[4]) {
        const int k = it * BK + sslot * 8;
        const bool v = (k < KDIM) & (garow < B);   // 784 % 8 == 0: chunk all-in or all-out
        float4 z = make_float4(0.f, 0.f, 0.f, 0.f);
        R[0] = v ? *(const float4*)(xrow + k)     : z;
        R[1] = v ? *(const float4*)(xrow + k + 4) : z;
        R[2] = (k < KDIM) ? *(const float4*)(wrow + k)     : z;
        R[3] = (k < KDIM) ? *(const float4*)(wrow + k + 4) : z;
    };

    auto step = [&](int it, float4 (&R)[4]) {
        // store phase: consume tile `it` (compiler emits counted vmcnt for R)
        uint4 pa = make_uint4(pack2(R[0].x, R[0].y), pack2(R[0].z, R[0].w),
                              pack2(R[1].x, R[1].y), pack2(R[1].z, R[1].w));
        uint4 pb = make_uint4(pack2(R[2].x, R[2].y), pack2(R[2].z, R[2].w),
                              pack2(R[3].x, R[3].y), pack2(R[3].z, R[3].w));
        *(uint4*)(lds.u.st.a + srow * ASTR + sslot * 16) = pa;
        *(uint4*)(lds.u.st.b + srow * ASTR + sslot * 16) = pb;
        if (it + 2 < NITER) loadTile(it + 2, R);   // refill same set; stays in flight
        asm volatile("s_waitcnt lgkmcnt(0)" ::: "memory");   // my ds_writes done
        __builtin_amdgcn_s_barrier();                        // tile complete (no vmcnt drain)
        // fragments + 4 MFMA: wave owns rows [wave*16, wave*16+16), all 64 cols
        const char* abase = lds.u.st.a + (wave * 16 + (lane & 15)) * ASTR + (lane >> 4) * 16;
        s16x8 af = *(const s16x8*)abase;
        const char* bbase = lds.u.st.b + (lane & 15) * ASTR + (lane >> 4) * 16;
        #pragma unroll
        for (int n = 0; n < 4; ++n) {
            s16x8 bf = *(const s16x8*)(bbase + n * 16 * ASTR);
            acc[n] = __builtin_amdgcn_mfma_f32_16x16x32_bf16(af, bf, acc[n], 0, 0, 0);
        }
        asm volatile("s_waitcnt lgkmcnt(0)" ::: "memory");   // my ds_reads done
        __builtin_amdgcn_s_barrier();                        // safe to overwrite
    };

    loadTile(0, Ra);
    loadTile(1, Rb);
    for (int i = 0; i < 12; ++i) {     // iters 0..23 in parity pairs
        step(2 * i,     Ra);
        step(2 * i + 1, Rb);
    }
    step(24, Ra);                      // last iter (no prefetch inside)

    // epilogue: h1 = relu(acc + b1) into LDS (stride 65).
    // C layout (m89): col = n*16 + (lane&15), row = (lane>>4)*4 + j
    #pragma unroll
    for (int n = 0; n < 4; ++n) {
        int c = n * 16 + (lane & 15);
        float bias = b1[c];
        #pragma unroll
        for (int j = 0; j < 4; ++j) {
            int r = wave * 16 + (lane >> 4) * 4 + j;
            lds.u.h1[r * 65 + c] = fmaxf(acc[n][j] + bias, 0.f);
        }
    }
    __syncthreads();

    // layers 2+3: wave g computes h2[g*4 .. g*4+4) for row = lane (W2 rows wave-uniform -> s_load)
    {
        const int g = wave, row = lane;
        const float* h1p = &lds.u.h1[row * 65];
        float a1p = 0.f, a2p = 0.f;
        #pragma unroll
        for (int jj = 0; jj < 4; ++jj) {
            int j2 = g * 4 + jj;
            float s = b2[j2];
            #pragma unroll
            for (int k = 0; k < 64; ++k) s = fmaf(h1p[k], W2[j2 * 64 + k], s);
            s = fmaxf(s, 0.f);
            a1p = fmaf(s, W3[16 + j2], a1p);
            a2p = fmaf(s, W3[32 + j2], a2p);
        }
        lds.part[g][row][0] = a1p;
        lds.part[g][row][1] = a2p;
    }
    __syncthreads();

    if (tid < BM) {
        int grow = row0 + tid;
        if (grow < B) {
            float a1 = b3[1] + lds.part[0][tid][0] + lds.part[1][tid][0]
                             + lds.part[2][tid][0] + lds.part[3][tid][0];
            float a2 = b3[2] + lds.part[0][tid][1] + lds.part[1][tid][1]
                             + lds.part[2][tid][1] + lds.part[3][tid][1];
            float t1 = 1.f - 2.f / (__expf(2.f * a1) + 1.f);   // tanh
            float t2 = 1.f - 2.f / (__expf(2.f * a2) + 1.f);
            const float PI = 3.14159265358979323846f;
            float z0 = __sinf(PI * t1) * __sinf(PI * t2);
            out[grow] = 1.f / (1.f + __expf(-5.f * z0));
        }
    }
}

extern "C" void kernel_launch(void* const* d_in, const int* in_sizes, int n_in,
                              void* d_out, int out_size, void* d_ws, size_t ws_size,
                              hipStream_t stream) {
    const float* x  = (const float*)d_in[0];
    const float* W1 = (const float*)d_in[1];
    const float* b1 = (const float*)d_in[2];
    const float* W2 = (const float*)d_in[3];
    const float* b2 = (const float*)d_in[4];
    const float* W3 = (const float*)d_in[5];
    const float* b3 = (const float*)d_in[6];
    // d_in[7] = q_params: unused (RZ phases cancel in |psi|^2)
    int B = in_sizes[0] / KDIM;
    int grid = (B + BM - 1) / BM;
    hybrid_kernel<<<grid, 256, 0, stream>>>(x, W1, b1, W2, b2, W3, b3, (float*)d_out, B);
}

// Round 3
// 47.553 us; speedup vs baseline: 1.2503x; 1.2503x over previous
//
#include <hip/hip_runtime.h>
#include <hip/hip_bf16.h>

// Analytic reduction of the reference:
//   angles = pi*tanh(MLP(x));  <Z0> = sin(theta1)*sin(theta2)  (theta0, q_params cancel)
//   out = sigmoid(5*<Z0>)
// Memory-bound on streaming x (205 MB). Round 3: barrier-free main loop.
//   - W1 staged ONCE into LDS in MFMA B-fragment order (100 KB), one barrier.
//   - x loaded wave-private global->reg (each wave owns its 16 rows) -> no LDS
//     staging, no ds_write, no per-tile barriers, no vmcnt(0) drains.
//   - 1024 thr (16 waves), 256 rows/block, grid = B/256 = 1 block/CU.

#define KDIM 784
#define BMB 256
#define NSTEP 25          // ceil(784/32); step 24 is a half tile (k=768..783)
#define H1STR 66          // h1 LDS stride (words): 2-way banks on r/w (free)

using f32x4 = __attribute__((ext_vector_type(4))) float;
using s16x8 = __attribute__((ext_vector_type(8))) short;

union LdsU {
    uint4 bfr[NSTEP * 4 * 64];            // 102400 B: W1, frag order [step][n][lane]
    struct {
        float h1[BMB * H1STR];            // 67584 B
        float part[4][BMB][2];            // 8192 B
    } t;
};

__device__ __forceinline__ ushort f2bf(float f) {
    uint b = __float_as_uint(f);
    b += 0x7FFFu + ((b >> 16) & 1u);      // RNE
    return (ushort)(b >> 16);
}
__device__ __forceinline__ uint pack2(float lo, float hi) {
    return (uint)f2bf(lo) | ((uint)f2bf(hi) << 16);
}
__device__ __forceinline__ uint4 pack8(float4 a, float4 b) {
    return make_uint4(pack2(a.x, a.y), pack2(a.z, a.w),
                      pack2(b.x, b.y), pack2(b.z, b.w));
}
__device__ __forceinline__ s16x8 asfrag(uint4 p) {
    union { uint4 u; s16x8 s; } c; c.u = p; return c.s;
}

__global__ void __launch_bounds__(1024, 4) hybrid_kernel(
    const float* __restrict__ x, const float* __restrict__ W1,
    const float* __restrict__ b1, const float* __restrict__ W2,
    const float* __restrict__ b2, const float* __restrict__ W3,
    const float* __restrict__ b3, float* __restrict__ out, int B)
{
    __shared__ LdsU lds;
    const int tid  = threadIdx.x;
    const int wave = tid >> 6, lane = tid & 63;
    const int row0 = blockIdx.x * BMB;

    // A addressing: lane owns row (wave*16 + (lane&15)), k-offset (lane>>4)*8
    const int kl   = (lane >> 4) << 3;
    int arow = row0 + wave * 16 + (lane & 15);
    arow = arow < B ? arow : B - 1;                  // clamp (B%256==0 in practice)
    const float* abase = x + (size_t)arow * KDIM + kl;

    // issue step-0 A loads first: in flight during W1 staging
    float4 c0 = *(const float4*)(abase);
    float4 c1 = *(const float4*)(abase + 4);

    // stage W1 -> LDS in B-frag order: chunk c = (step, n, lane16B)
    for (int c = tid; c < NSTEP * 4 * 64; c += 1024) {
        int s = c >> 8, n = (c >> 6) & 3, l = c & 63;
        int k0  = s * 32 + ((l >> 4) << 3);
        int col = n * 16 + (l & 15);
        float4 w0 = make_float4(0.f, 0.f, 0.f, 0.f), w1 = w0;
        if (k0 < KDIM) {                             // tail zero-fill (784%8==0)
            const float* p = W1 + (size_t)col * KDIM + k0;
            w0 = *(const float4*)p;
            w1 = *(const float4*)(p + 4);
        }
        lds.bfr[c] = pack8(w0, w1);
    }

    f32x4 acc[4];
    #pragma unroll
    for (int n = 0; n < 4; ++n)
        #pragma unroll
        for (int j = 0; j < 4; ++j) acc[n][j] = 0.f;

    __syncthreads();                                 // W1 staged (once)

    // barrier-free main loop: global->reg A, LDS B (read-only), 4 MFMA / step
    #define STEP(s, u0, u1)                                                        \
        {                                                                          \
            s16x8 af = asfrag(pack8(u0, u1));                                      \
            const uint4* bp = &lds.bfr[(s) * 256 + lane];                          \
            _Pragma("unroll")                                                      \
            for (int n = 0; n < 4; ++n)                                            \
                acc[n] = __builtin_amdgcn_mfma_f32_16x16x32_bf16(                  \
                    af, asfrag(bp[n * 64]), acc[n], 0, 0, 0);                      \
        }

    for (int s = 0; s < 23; ++s) {                   // prefetch s+1 unguarded
        float4 n0 = *(const float4*)(abase + (s + 1) * 32);
        float4 n1 = *(const float4*)(abase + (s + 1) * 32 + 4);
        STEP(s, c0, c1);
        c0 = n0; c1 = n1;
    }
    {                                                // s=23: guarded prefetch of 24
        float4 n0 = make_float4(0.f, 0.f, 0.f, 0.f), n1 = n0;
        if (kl < KDIM - 768) {                       // lanes with k<784 only
            n0 = *(const float4*)(abase + 768);
            n1 = *(const float4*)(abase + 772);
        }
        STEP(23, c0, c1);
        c0 = n0; c1 = n1;
    }
    STEP(24, c0, c1);
    #undef STEP

    __syncthreads();                                 // all B-frag reads done; reuse LDS

    // h1 = relu(acc + b1); C layout (m89): col = n*16+(lane&15), row = (lane>>4)*4+j
    #pragma unroll
    for (int n = 0; n < 4; ++n) {
        int c = n * 16 + (lane & 15);
        float bias = b1[c];
        #pragma unroll
        for (int j = 0; j < 4; ++j) {
            int r = wave * 16 + (lane >> 4) * 4 + j;
            lds.t.h1[r * H1STR + c] = fmaxf(acc[n][j] + bias, 0.f);
        }
    }
    __syncthreads();

    // layers 2+3: row = tid&255, q = tid>>8 (q wave-uniform -> W2 via s_load)
    {
        const int row = tid & 255, q = tid >> 8;
        const float* h1p = &lds.t.h1[row * H1STR];
        float4 hv[16];
        #pragma unroll
        for (int k4 = 0; k4 < 16; ++k4) hv[k4] = *(const float4*)(h1p + k4 * 4);
        float a1 = 0.f, a2 = 0.f;
        #pragma unroll
        for (int jj = 0; jj < 4; ++jj) {
            int j2 = q * 4 + jj;
            float s = b2[j2];
            #pragma unroll
            for (int k4 = 0; k4 < 16; ++k4) {
                const float4 w = *(const float4*)(W2 + j2 * 64 + k4 * 4);
                s = fmaf(hv[k4].x, w.x, s); s = fmaf(hv[k4].y, w.y, s);
                s = fmaf(hv[k4].z, w.z, s); s = fmaf(hv[k4].w, w.w, s);
            }
            s = fmaxf(s, 0.f);
            a1 = fmaf(s, W3[16 + j2], a1);
            a2 = fmaf(s, W3[32 + j2], a2);
        }
        lds.t.part[q][row][0] = a1;
        lds.t.part[q][row][1] = a2;
    }
    __syncthreads();

    if (tid < BMB) {
        int grow = row0 + tid;
        if (grow < B) {
            float a1 = b3[1] + lds.t.part[0][tid][0] + lds.t.part[1][tid][0]
                             + lds.t.part[2][tid][0] + lds.t.part[3][tid][0];
            float a2 = b3[2] + lds.t.part[0][tid][1] + lds.t.part[1][tid][1]
                             + lds.t.part[2][tid][1] + lds.t.part[3][tid][1];
            float t1 = 1.f - 2.f / (__expf(2.f * a1) + 1.f);   // tanh
            float t2 = 1.f - 2.f / (__expf(2.f * a2) + 1.f);
            const float PI = 3.14159265358979323846f;
            float z0 = __sinf(PI * t1) * __sinf(PI * t2);
            out[grow] = 1.f / (1.f + __expf(-5.f * z0));
        }
    }
}

extern "C" void kernel_launch(void* const* d_in, const int* in_sizes, int n_in,
                              void* d_out, int out_size, void* d_ws, size_t ws_size,
                              hipStream_t stream) {
    const float* x  = (const float*)d_in[0];
    const float* W1 = (const float*)d_in[1];
    const float* b1 = (const float*)d_in[2];
    const float* W2 = (const float*)d_in[3];
    const float* b2 = (const float*)d_in[4];
    const float* W3 = (const float*)d_in[5];
    const float* b3 = (const float*)d_in[6];
    // d_in[7] = q_params: unused (RZ phases cancel in |psi|^2)
    int B = in_sizes[0] / KDIM;
    int grid = (B + BMB - 1) / BMB;
    hybrid_kernel<<<grid, 1024, 0, stream>>>(x, W1, b1, W2, b2, W3, b3, (float*)d_out, B);
}